// Round 6
// baseline (309.560 us; speedup 1.0000x reference)
//
#include <hip/hip_runtime.h>
#include <math.h>

#define NN 4
#define TMAX 20
#define EPS 1e-6f
#define POST_MULT 2.0f

typedef float vfloat4 __attribute__((ext_vector_type(4)));

// ---------------------------------------------------------------------------
// Kernel 1 (proven): 16 lanes per t, shuffle Sinkhorn, coeffs -> ws. ~4 us.
// ---------------------------------------------------------------------------
__global__ __launch_bounds__(256) void coeff_kernel(
    const float* __restrict__ mix,        // (T, 24)
    const float* __restrict__ invr,       // (T,)
    const float* __restrict__ alpha_pre,  // (1,)
    const float* __restrict__ alpha_post, // (1,)
    const float* __restrict__ alpha_res,  // (1,)
    const float* __restrict__ bias,       // (24,)
    float* __restrict__ coeffs,           // (T, 24) in ws
    int T)
{
    const int gtid = blockIdx.x * blockDim.x + threadIdx.x;
    const int t    = gtid >> 4;
    const int lane = gtid & 15;
    if (t >= T) return;

    const float ir = invr[t];

    float r = mix[t * 24 + 8 + lane] * ir * alpha_res[0] + bias[8 + lane];
    float m = r;
    m = fmaxf(m, __shfl_xor(m, 1));
    m = fmaxf(m, __shfl_xor(m, 2));
    r = __expf(r - m);
    #pragma unroll
    for (int it = 0; it < TMAX; ++it) {
        float rs = r;                       // row sum (over j)
        rs += __shfl_xor(rs, 1);
        rs += __shfl_xor(rs, 2);
        r = r / (rs + EPS);
        float cs = r;                       // col sum (over i)
        cs += __shfl_xor(cs, 4);
        cs += __shfl_xor(cs, 8);
        r = r / (cs + EPS);
    }
    coeffs[t * 24 + 8 + lane] = r;

    if (lane < 8) {
        const float a = (lane < NN) ? alpha_pre[0] : alpha_post[0];
        const float z = mix[t * 24 + lane] * ir * a + bias[lane];
        float sg = 1.0f / (1.0f + __expf(-z));
        if (lane >= NN) sg *= POST_MULT;
        coeffs[t * 24 + lane] = sg;
    }
}

// ---------------------------------------------------------------------------
// Kernel 2 (shape-specialized, C==1024, T%4==0): STRAIGHT-LINE 4-t batch.
// Grid = T/4 blocks x 256 threads. Block b owns t0=4b..4b+3; thread tid owns
// strip v=tid of all four t's. The body has NO loops with runtime bounds, NO
// guards, NO loop-carried values: 20 independent b128 loads are emitted
// first (the compiler defeated this batch in rounds 2 and 4 via guards /
// carried copies -> 40/64 VGPR; success signature this time is VGPR >= ~100),
// then per-t compute + NT stores (NT proven +10% in round 3). Coefficient
// addresses are block-uniform -> pure scalar loads. Contiguous 4-t blocks
// keep the L3 read-residency (round 5's i/i+M/2 split put each wave's two
// streams 80 MB apart).
// ---------------------------------------------------------------------------
#define NVC 256   // C/4 strips per row, == blockDim

__global__ __launch_bounds__(256) void stream4_kernel(
    const float* __restrict__ x,       // (T, 4, 1024)
    const float* __restrict__ f_out,   // (T, 1024)
    const float* __restrict__ coeffs,  // (T, 24)
    float* __restrict__ y_pre,         // (T, 1024)
    float* __restrict__ out)           // (T, 4, 1024)
{
    const int t0 = blockIdx.x << 2;
    const int v  = threadIdx.x;        // 0..255 == strip index

    // --- issue all 20 independent b128 loads first ---
    vfloat4 xd[4][NN];
    vfloat4 fd[4];
    #pragma unroll
    for (int k = 0; k < 4; ++k) {
        const vfloat4* xp = (const vfloat4*)x + (size_t)(t0 + k) * NN * NVC;
        #pragma unroll
        for (int n = 0; n < NN; ++n) xd[k][n] = xp[n * NVC + v];
        fd[k] = ((const vfloat4*)f_out)[(size_t)(t0 + k) * NVC + v];
    }

    // --- per-t compute + NT stores (coeffs are block-uniform -> s_loads) ---
    #pragma unroll
    for (int k = 0; k < 4; ++k) {
        const float* cf = coeffs + (size_t)(t0 + k) * 24;

        vfloat4* yp4 = (vfloat4*)y_pre + (size_t)(t0 + k) * NVC;
        vfloat4* o4  = (vfloat4*)out + (size_t)(t0 + k) * NN * NVC;

        vfloat4 yv = cf[0] * xd[k][0] + cf[1] * xd[k][1]
                   + cf[2] * xd[k][2] + cf[3] * xd[k][3];
        __builtin_nontemporal_store(yv, &yp4[v]);

        #pragma unroll
        for (int j = 0; j < NN; ++j) {
            vfloat4 ov = cf[4 + j] * fd[k];
            #pragma unroll
            for (int i = 0; i < NN; ++i) ov += cf[8 + j * 4 + i] * xd[k][i];
            __builtin_nontemporal_store(ov, &o4[j * NVC + v]);
        }
    }
}

// ---------------------------------------------------------------------------
// Generic fallback (round-5 persistent grid-stride kernel).
// ---------------------------------------------------------------------------
__device__ __forceinline__ void process_item(
    long i, int sh, int NV,
    const float* __restrict__ x, const float* __restrict__ f_out,
    const float* __restrict__ coeffs,
    float* __restrict__ y_pre, float* __restrict__ out)
{
    const int t = (int)(i >> sh);
    const int v = (int)(i & (NV - 1));

    const int ts = __builtin_amdgcn_readfirstlane(t);
    const float* cf = coeffs + (size_t)ts * 24;

    const vfloat4* xv4 = (const vfloat4*)x + (size_t)t * NN * NV;
    const vfloat4* fv4 = (const vfloat4*)f_out + (size_t)t * NV;
    vfloat4* yp4 = (vfloat4*)y_pre + (size_t)t * NV;
    vfloat4* o4  = (vfloat4*)out + (size_t)t * NN * NV;

    vfloat4 xv[NN];
    #pragma unroll
    for (int n = 0; n < NN; ++n) xv[n] = xv4[n * NV + v];
    const vfloat4 fv = fv4[v];

    vfloat4 yv = cf[0] * xv[0] + cf[1] * xv[1] + cf[2] * xv[2] + cf[3] * xv[3];
    __builtin_nontemporal_store(yv, &yp4[v]);

    #pragma unroll
    for (int j = 0; j < NN; ++j) {
        vfloat4 ov = cf[4 + j] * fv;
        #pragma unroll
        for (int ii = 0; ii < NN; ++ii) ov += cf[8 + j * 4 + ii] * xv[ii];
        __builtin_nontemporal_store(ov, &o4[j * NV + v]);
    }
}

__global__ __launch_bounds__(256) void stream_fallback(
    const float* __restrict__ x, const float* __restrict__ f_out,
    const float* __restrict__ coeffs,
    float* __restrict__ y_pre, float* __restrict__ out, int C, int T)
{
    const int NV = C >> 2;
    const bool pow2 = NV > 0 && (NV & (NV - 1)) == 0;
    if (pow2) {
        const int sh = 31 - __clz(NV);
        const long M = (long)T << sh;
        const long stride = (long)gridDim.x * blockDim.x;
        for (long i = (long)blockIdx.x * blockDim.x + threadIdx.x; i < M;
             i += stride)
            process_item(i, sh, NV, x, f_out, coeffs, y_pre, out);
    } else {
        // very generic: one block per t
        const int t   = blockIdx.x % T;
        const int tid = threadIdx.x;
        const float* cf = coeffs + (size_t)t * 24;
        const vfloat4* xv4 = (const vfloat4*)(x + (size_t)t * NN * C);
        const vfloat4* fv4 = (const vfloat4*)(f_out + (size_t)t * C);
        vfloat4* yp4 = (vfloat4*)(y_pre + (size_t)t * C);
        vfloat4* o4  = (vfloat4*)(out + (size_t)t * NN * C);
        for (int v = tid; v < NV; v += blockDim.x) {
            vfloat4 xv[NN];
            #pragma unroll
            for (int n = 0; n < NN; ++n) xv[n] = xv4[n * NV + v];
            const vfloat4 fv = fv4[v];
            vfloat4 yv = cf[0]*xv[0] + cf[1]*xv[1] + cf[2]*xv[2] + cf[3]*xv[3];
            __builtin_nontemporal_store(yv, &yp4[v]);
            #pragma unroll
            for (int j = 0; j < NN; ++j) {
                vfloat4 ov = cf[4 + j] * fv;
                #pragma unroll
                for (int i = 0; i < NN; ++i) ov += cf[8 + j*4 + i] * xv[i];
                __builtin_nontemporal_store(ov, &o4[j * NV + v]);
            }
        }
    }
}

extern "C" void kernel_launch(void* const* d_in, const int* in_sizes, int n_in,
                              void* d_out, int out_size, void* d_ws, size_t ws_size,
                              hipStream_t stream) {
    const float* x          = (const float*)d_in[0];
    const float* f_out      = (const float*)d_in[1];
    const float* mix        = (const float*)d_in[2];
    const float* invr       = (const float*)d_in[3];
    const float* alpha_pre  = (const float*)d_in[4];
    const float* alpha_post = (const float*)d_in[5];
    const float* alpha_res  = (const float*)d_in[6];
    const float* bias       = (const float*)d_in[7];

    const int T = in_sizes[3];               // invr is (T,)
    const int C = in_sizes[1] / T;           // f_out is (T, C)

    float* y_pre = (float*)d_out;                   // (T, C)
    float* out   = (float*)d_out + (size_t)T * C;   // (T, N, C)
    float* coeffs = (float*)d_ws;                   // (T, 24)

    const int grid1 = (T * 16 + 255) / 256;
    coeff_kernel<<<grid1, 256, 0, stream>>>(mix, invr, alpha_pre, alpha_post,
                                            alpha_res, bias, coeffs, T);

    if (C == 1024 && (T % 4) == 0) {
        stream4_kernel<<<T / 4, 256, 0, stream>>>(x, f_out, coeffs, y_pre, out);
    } else {
        stream_fallback<<<2048, 256, 0, stream>>>(x, f_out, coeffs, y_pre, out,
                                                  C, T);
    }
}

// Round 7
// 308.038 us; speedup vs baseline: 1.0049x; 1.0049x over previous
//
#include <hip/hip_runtime.h>
#include <math.h>

#define NN 4
#define TMAX 20
#define EPS 1e-6f
#define POST_MULT 2.0f

typedef float vfloat4 __attribute__((ext_vector_type(4)));

// ---------------------------------------------------------------------------
// Kernel 1 (proven): 16 lanes per t, shuffle Sinkhorn, coeffs -> ws. ~4 us.
// ---------------------------------------------------------------------------
__global__ __launch_bounds__(256) void coeff_kernel(
    const float* __restrict__ mix,        // (T, 24)
    const float* __restrict__ invr,       // (T,)
    const float* __restrict__ alpha_pre,  // (1,)
    const float* __restrict__ alpha_post, // (1,)
    const float* __restrict__ alpha_res,  // (1,)
    const float* __restrict__ bias,       // (24,)
    float* __restrict__ coeffs,           // (T, 24) in ws
    int T)
{
    const int gtid = blockIdx.x * blockDim.x + threadIdx.x;
    const int t    = gtid >> 4;
    const int lane = gtid & 15;
    if (t >= T) return;

    const float ir = invr[t];

    float r = mix[t * 24 + 8 + lane] * ir * alpha_res[0] + bias[8 + lane];
    float m = r;
    m = fmaxf(m, __shfl_xor(m, 1));
    m = fmaxf(m, __shfl_xor(m, 2));
    r = __expf(r - m);
    #pragma unroll
    for (int it = 0; it < TMAX; ++it) {
        float rs = r;                       // row sum (over j)
        rs += __shfl_xor(rs, 1);
        rs += __shfl_xor(rs, 2);
        r = r / (rs + EPS);
        float cs = r;                       // col sum (over i)
        cs += __shfl_xor(cs, 4);
        cs += __shfl_xor(cs, 8);
        r = r / (cs + EPS);
    }
    coeffs[t * 24 + 8 + lane] = r;

    if (lane < 8) {
        const float a = (lane < NN) ? alpha_pre[0] : alpha_post[0];
        const float z = mix[t * 24 + lane] * ir * a + bias[lane];
        float sg = 1.0f / (1.0f + __expf(-z));
        if (lane >= NN) sg *= POST_MULT;
        coeffs[t * 24 + lane] = sg;
    }
}

// ---------------------------------------------------------------------------
// Kernel 2 (shape-specialized, C==1024, T%4==0): straight-line 4-t batch.
// SINGLE CHANGE vs round 6: __builtin_amdgcn_sched_barrier(0) between the
// 20-load cluster and the compute/store section, + __launch_bounds__(256,1)
// so the register allocator may hold all 20 b128 results live.
// Round-6 evidence: without the barrier the machine scheduler sank the loads
// to their uses (VGPR=32 -> <=5 loads in flight, near-vmcnt(0) waits that
// also drain in-flight NT stores -> 2.4 TB/s). The barrier is a pure
// scheduling directive: the compiler still emits correct, COUNTED waitcnts
// (t0 compute at vmcnt(15) while t1..t3 loads are in flight).
// Success signature: VGPR >= ~96.
// ---------------------------------------------------------------------------
#define NVC 256   // C/4 strips per row, == blockDim

__global__ __launch_bounds__(256, 1) void stream4_kernel(
    const float* __restrict__ x,       // (T, 4, 1024)
    const float* __restrict__ f_out,   // (T, 1024)
    const float* __restrict__ coeffs,  // (T, 24)
    float* __restrict__ y_pre,         // (T, 1024)
    float* __restrict__ out)           // (T, 4, 1024)
{
    const int t0 = blockIdx.x << 2;
    const int v  = threadIdx.x;        // 0..255 == strip index

    // --- issue all 20 independent b128 loads first ---
    vfloat4 xd[4][NN];
    vfloat4 fd[4];
    #pragma unroll
    for (int k = 0; k < 4; ++k) {
        const vfloat4* xp = (const vfloat4*)x + (size_t)(t0 + k) * NN * NVC;
        #pragma unroll
        for (int n = 0; n < NN; ++n) xd[k][n] = xp[n * NVC + v];
        fd[k] = ((const vfloat4*)f_out)[(size_t)(t0 + k) * NVC + v];
    }

    // Nothing may be scheduled across this point: the load cluster stays a
    // cluster, all 20 results stay live -> deep MLP actually exists.
    __builtin_amdgcn_sched_barrier(0);

    // --- per-t compute + NT stores (coeffs are block-uniform -> s_loads) ---
    #pragma unroll
    for (int k = 0; k < 4; ++k) {
        const float* cf = coeffs + (size_t)(t0 + k) * 24;

        vfloat4* yp4 = (vfloat4*)y_pre + (size_t)(t0 + k) * NVC;
        vfloat4* o4  = (vfloat4*)out + (size_t)(t0 + k) * NN * NVC;

        vfloat4 yv = cf[0] * xd[k][0] + cf[1] * xd[k][1]
                   + cf[2] * xd[k][2] + cf[3] * xd[k][3];
        __builtin_nontemporal_store(yv, &yp4[v]);

        #pragma unroll
        for (int j = 0; j < NN; ++j) {
            vfloat4 ov = cf[4 + j] * fd[k];
            #pragma unroll
            for (int i = 0; i < NN; ++i) ov += cf[8 + j * 4 + i] * xd[k][i];
            __builtin_nontemporal_store(ov, &o4[j * NVC + v]);
        }
    }
}

// ---------------------------------------------------------------------------
// Generic fallback (round-5 persistent grid-stride kernel).
// ---------------------------------------------------------------------------
__device__ __forceinline__ void process_item(
    long i, int sh, int NV,
    const float* __restrict__ x, const float* __restrict__ f_out,
    const float* __restrict__ coeffs,
    float* __restrict__ y_pre, float* __restrict__ out)
{
    const int t = (int)(i >> sh);
    const int v = (int)(i & (NV - 1));

    const int ts = __builtin_amdgcn_readfirstlane(t);
    const float* cf = coeffs + (size_t)ts * 24;

    const vfloat4* xv4 = (const vfloat4*)x + (size_t)t * NN * NV;
    const vfloat4* fv4 = (const vfloat4*)f_out + (size_t)t * NV;
    vfloat4* yp4 = (vfloat4*)y_pre + (size_t)t * NV;
    vfloat4* o4  = (vfloat4*)out + (size_t)t * NN * NV;

    vfloat4 xv[NN];
    #pragma unroll
    for (int n = 0; n < NN; ++n) xv[n] = xv4[n * NV + v];
    const vfloat4 fv = fv4[v];

    vfloat4 yv = cf[0] * xv[0] + cf[1] * xv[1] + cf[2] * xv[2] + cf[3] * xv[3];
    __builtin_nontemporal_store(yv, &yp4[v]);

    #pragma unroll
    for (int j = 0; j < NN; ++j) {
        vfloat4 ov = cf[4 + j] * fv;
        #pragma unroll
        for (int ii = 0; ii < NN; ++ii) ov += cf[8 + j * 4 + ii] * xv[ii];
        __builtin_nontemporal_store(ov, &o4[j * NV + v]);
    }
}

__global__ __launch_bounds__(256) void stream_fallback(
    const float* __restrict__ x, const float* __restrict__ f_out,
    const float* __restrict__ coeffs,
    float* __restrict__ y_pre, float* __restrict__ out, int C, int T)
{
    const int NV = C >> 2;
    const bool pow2 = NV > 0 && (NV & (NV - 1)) == 0;
    if (pow2) {
        const int sh = 31 - __clz(NV);
        const long M = (long)T << sh;
        const long stride = (long)gridDim.x * blockDim.x;
        for (long i = (long)blockIdx.x * blockDim.x + threadIdx.x; i < M;
             i += stride)
            process_item(i, sh, NV, x, f_out, coeffs, y_pre, out);
    } else {
        const int t   = blockIdx.x % T;
        const int tid = threadIdx.x;
        const float* cf = coeffs + (size_t)t * 24;
        const vfloat4* xv4 = (const vfloat4*)(x + (size_t)t * NN * C);
        const vfloat4* fv4 = (const vfloat4*)(f_out + (size_t)t * C);
        vfloat4* yp4 = (vfloat4*)(y_pre + (size_t)t * C);
        vfloat4* o4  = (vfloat4*)(out + (size_t)t * NN * C);
        for (int v = tid; v < NV; v += blockDim.x) {
            vfloat4 xv[NN];
            #pragma unroll
            for (int n = 0; n < NN; ++n) xv[n] = xv4[n * NV + v];
            const vfloat4 fv = fv4[v];
            vfloat4 yv = cf[0]*xv[0] + cf[1]*xv[1] + cf[2]*xv[2] + cf[3]*xv[3];
            __builtin_nontemporal_store(yv, &yp4[v]);
            #pragma unroll
            for (int j = 0; j < NN; ++j) {
                vfloat4 ov = cf[4 + j] * fv;
                #pragma unroll
                for (int i = 0; i < NN; ++i) ov += cf[8 + j*4 + i] * xv[i];
                __builtin_nontemporal_store(ov, &o4[j * NV + v]);
            }
        }
    }
}

extern "C" void kernel_launch(void* const* d_in, const int* in_sizes, int n_in,
                              void* d_out, int out_size, void* d_ws, size_t ws_size,
                              hipStream_t stream) {
    const float* x          = (const float*)d_in[0];
    const float* f_out      = (const float*)d_in[1];
    const float* mix        = (const float*)d_in[2];
    const float* invr       = (const float*)d_in[3];
    const float* alpha_pre  = (const float*)d_in[4];
    const float* alpha_post = (const float*)d_in[5];
    const float* alpha_res  = (const float*)d_in[6];
    const float* bias       = (const float*)d_in[7];

    const int T = in_sizes[3];               // invr is (T,)
    const int C = in_sizes[1] / T;           // f_out is (T, C)

    float* y_pre = (float*)d_out;                   // (T, C)
    float* out   = (float*)d_out + (size_t)T * C;   // (T, N, C)
    float* coeffs = (float*)d_ws;                   // (T, 24)

    const int grid1 = (T * 16 + 255) / 256;
    coeff_kernel<<<grid1, 256, 0, stream>>>(mix, invr, alpha_pre, alpha_post,
                                            alpha_res, bias, coeffs, T);

    if (C == 1024 && (T % 4) == 0) {
        stream4_kernel<<<T / 4, 256, 0, stream>>>(x, f_out, coeffs, y_pre, out);
    } else {
        stream_fallback<<<2048, 256, 0, stream>>>(x, f_out, coeffs, y_pre, out,
                                                  C, T);
    }
}